// Round 5
// baseline (144.181 us; speedup 1.0000x reference)
//
#include <hip/hip_runtime.h>

#define B_ 4
#define S_ 1024
#define D_ 1024
#define H_ 16
#define DK_ 64

typedef __attribute__((ext_vector_type(8))) short short8;
typedef __attribute__((ext_vector_type(4))) float f32x4;
typedef __attribute__((ext_vector_type(16))) float f32x16;

static __device__ __forceinline__ unsigned bf16rne(float x) {
    unsigned b = __float_as_uint(x);
    return (b + 0x7FFFu + ((b >> 16) & 1u)) >> 16;
}

// ---------------------------------------------------------------------------
// fp32 -> bf16 convert for q,k,v in one launch (outputs contiguous).
// ---------------------------------------------------------------------------
__global__ __launch_bounds__(256) void cvt3_bf16(
    const float* __restrict__ q, const float* __restrict__ k,
    const float* __restrict__ v, ushort* __restrict__ out)
{
    const size_t i = ((size_t)blockIdx.x * 256 + threadIdx.x) * 8;
    const size_t FM = (size_t)4 * 1024 * 1024;
    const float* in = (i < FM) ? q : (i < 2 * FM) ? k : v;
    const size_t off = i & (FM - 1);
    const float4 a = *reinterpret_cast<const float4*>(in + off);
    const float4 b = *reinterpret_cast<const float4*>(in + off + 4);
    union { ushort u[8]; int4 vv; } p;
    p.u[0] = (ushort)bf16rne(a.x); p.u[1] = (ushort)bf16rne(a.y);
    p.u[2] = (ushort)bf16rne(a.z); p.u[3] = (ushort)bf16rne(a.w);
    p.u[4] = (ushort)bf16rne(b.x); p.u[5] = (ushort)bf16rne(b.y);
    p.u[6] = (ushort)bf16rne(b.z); p.u[7] = (ushort)bf16rne(b.w);
    *reinterpret_cast<int4*>(out + i) = p.vv;
}

// ---------------------------------------------------------------------------
// W [1024][1024] fp32 -> Wt [n][k] bf16 (transpose + convert). z selects W.
// ---------------------------------------------------------------------------
__global__ __launch_bounds__(256) void transpose_cvt3(
    const float* __restrict__ W0, const float* __restrict__ W1,
    const float* __restrict__ W2, ushort* __restrict__ T0,
    ushort* __restrict__ T1, ushort* __restrict__ T2)
{
    __shared__ float ts[32][33];
    const float* W = (blockIdx.z == 0) ? W0 : (blockIdx.z == 1) ? W1 : W2;
    ushort*     Wt = (blockIdx.z == 0) ? T0 : (blockIdx.z == 1) ? T1 : T2;
    const int t  = threadIdx.x;
    const int k0 = blockIdx.y * 32, n0 = blockIdx.x * 32;
    const int r  = t >> 3, c4 = (t & 7) * 4;
    const float4 v = *reinterpret_cast<const float4*>(&W[(size_t)(k0 + r) * 1024 + n0 + c4]);
    ts[r][c4] = v.x; ts[r][c4 + 1] = v.y; ts[r][c4 + 2] = v.z; ts[r][c4 + 3] = v.w;
    __syncthreads();
    ushort4 o;
    o.x = (ushort)bf16rne(ts[c4    ][r]);
    o.y = (ushort)bf16rne(ts[c4 + 1][r]);
    o.z = (ushort)bf16rne(ts[c4 + 2][r]);
    o.w = (ushort)bf16rne(ts[c4 + 3][r]);
    *reinterpret_cast<ushort4*>(&Wt[(size_t)(n0 + r) * 1024 + k0 + c4]) = o;
}

// ---------------------------------------------------------------------------
// bf16 MFMA GEMM: C[M,1024] = X[M,1024] @ Wt^T (+bias, +resid).
// BM=64, BN=128, BK=64; 4 waves (2x2). Unchanged from R4.
// ---------------------------------------------------------------------------
template<int MODE>
__global__ __launch_bounds__(256) void gemm_mfma(
    const ushort* __restrict__ X, const ushort* __restrict__ Wt,
    const float* __restrict__ bias, const float* __restrict__ resid,
    void* __restrict__ out0, void* __restrict__ out1)
{
    __shared__ ushort As[64 * 64];
    __shared__ ushort Bs[128 * 64];

    const int t    = threadIdx.x;
    const int lane = t & 63;
    const int w    = t >> 6;

    const int cpx     = gridDim.x >> 3;
    const int logical = (blockIdx.x & 7) * cpx + (blockIdx.x >> 3);
    const int bm = logical >> 3;
    const int bn = logical & 7;

    const int srow   = lane >> 3;
    const int schunk = (lane & 7) ^ srow;
    const ushort* ag[2];
    const ushort* bg[4];
#pragma unroll
    for (int j = 0; j < 2; ++j)
        ag[j] = X  + (size_t)(bm * 64 + (j * 4 + w) * 8 + srow) * 1024 + schunk * 8;
#pragma unroll
    for (int j = 0; j < 4; ++j)
        bg[j] = Wt + (size_t)(bn * 128 + (j * 4 + w) * 8 + srow) * 1024 + schunk * 8;

#define STAGE(k0)                                                                \
    do {                                                                         \
        _Pragma("unroll")                                                        \
        for (int j = 0; j < 2; ++j)                                              \
            __builtin_amdgcn_global_load_lds(                                    \
                (__attribute__((address_space(1))) const void*)(ag[j] + (k0)),   \
                (__attribute__((address_space(3))) void*)&As[(j * 4 + w) * 512], \
                16, 0, 0);                                                       \
        _Pragma("unroll")                                                        \
        for (int j = 0; j < 4; ++j)                                              \
            __builtin_amdgcn_global_load_lds(                                    \
                (__attribute__((address_space(1))) const void*)(bg[j] + (k0)),   \
                (__attribute__((address_space(3))) void*)&Bs[(j * 4 + w) * 512], \
                16, 0, 0);                                                       \
    } while (0)

    const int fr = lane & 15;
    const int fk = lane >> 4;
    const int wm = w >> 1, wn = w & 1;

    f32x4 acc[2][4];
#pragma unroll
    for (int m = 0; m < 2; ++m)
#pragma unroll
        for (int n = 0; n < 4; ++n) acc[m][n] = (f32x4){0.f, 0.f, 0.f, 0.f};

#pragma unroll 1
    for (int kt = 0; kt < 16; ++kt) {
        STAGE(kt * 64);
        __syncthreads();
#pragma unroll
        for (int ks = 0; ks < 2; ++ks) {
            short8 af[2], bf[4];
#pragma unroll
            for (int m = 0; m < 2; ++m) {
                const int row = wm * 32 + m * 16 + fr;
                af[m] = *reinterpret_cast<const short8*>(
                    &As[row * 64 + (((ks * 4 + fk) ^ (row & 7)) * 8)]);
            }
#pragma unroll
            for (int n = 0; n < 4; ++n) {
                const int row = wn * 64 + n * 16 + fr;
                bf[n] = *reinterpret_cast<const short8*>(
                    &Bs[row * 64 + (((ks * 4 + fk) ^ (row & 7)) * 8)]);
            }
#pragma unroll
            for (int m = 0; m < 2; ++m)
#pragma unroll
                for (int n = 0; n < 4; ++n)
                    acc[m][n] = __builtin_amdgcn_mfma_f32_16x16x32_bf16(
                        af[m], bf[n], acc[m][n], 0, 0, 0);
        }
        __syncthreads();
    }
#undef STAGE

#pragma unroll
    for (int m = 0; m < 2; ++m) {
        const int row0 = bm * 64 + wm * 32 + m * 16 + fk * 4;
#pragma unroll
        for (int n = 0; n < 4; ++n) {
            const int col = bn * 128 + wn * 64 + n * 16 + fr;
            const float bc = bias[col];
            if (MODE == 0) {
                float* o = (float*)out0;
#pragma unroll
                for (int j = 0; j < 4; ++j) {
                    const int row = row0 + j;
                    o[(size_t)row * 1024 + col] =
                        acc[m][n][j] + bc + resid[(size_t)row * 1024 + col];
                }
            } else if (MODE == 1) {
                ushort* o = (row0 < 4096) ? (ushort*)out0 : (ushort*)out1;
                const int r0 = row0 & 4095;
                const int b_ = r0 >> 10, s0 = r0 & 1023;
                const int h  = col >> 6,  dk = col & 63;
#pragma unroll
                for (int j = 0; j < 4; ++j)
                    o[(((size_t)b_ * H_ + h) * S_ + s0 + j) * DK_ + dk] =
                        (ushort)bf16rne(acc[m][n][j] + bc);
            } else {
                ushort* o = (ushort*)out0;
                const int b_ = row0 >> 10, s0 = row0 & 1023;
                const int h  = col >> 6,   dk = col & 63;
                ushort4 pk;
                pk.x = (ushort)bf16rne(acc[m][n][0] + bc);
                pk.y = (ushort)bf16rne(acc[m][n][1] + bc);
                pk.z = (ushort)bf16rne(acc[m][n][2] + bc);
                pk.w = (ushort)bf16rne(acc[m][n][3] + bc);
                *reinterpret_cast<ushort4*>(
                    &o[(((size_t)b_ * H_ + h) * DK_ + dk) * S_ + s0]) = pk;
            }
        }
    }
}

// ---------------------------------------------------------------------------
// MFMA bf16 flash attention v3: split-K x2 (partition p covers k-tiles
// [p*(qb+1), (p+1)*(qb+1)) of the 2qb+2 total), fragment-major LDS layout
// (lane-linear ds_reads, zero bank conflicts), vmcnt-counted double buffer.
// Writes normalized partial ctx (bf16) + per-row (m,l) for the merge pass.
// ---------------------------------------------------------------------------
__global__ __launch_bounds__(256) void attn_mfma(
    const ushort* __restrict__ Qh, const ushort* __restrict__ Kh,
    const ushort* __restrict__ Vt, const float* __restrict__ SW,
    ushort* __restrict__ ctxP, float2* __restrict__ ml)
{
    __shared__ ushort Ks[2][4096];   // [buf][(g*4+c)*64 + lane] * 8 ushorts
    __shared__ ushort Vs[2][4096];

    const int t    = threadIdx.x;
    const int lane = t & 63;
    const int w    = t >> 6;
    const int bid  = blockIdx.x;          // 0..1023
    const int bh   = bid & 63;
    const int b    = bh >> 4;
    const int h    = bh & 15;
    const int qp   = bid >> 6;            // 0..15
    const int p    = qp >> 3;             // key partition 0/1
    int qb = qp & 7;
    qb = (qb < 4) ? qb : 11 - qb;         // pair heavy/light q-blocks

    const int ql = lane & 31;
    const int hi = lane >> 5;
    const int qrow = qb * 128 + ql * 4 + w;   // interleaved q-rows
    const int t0 = p * (qb + 1);              // first 64-key tile
    const int nt = qb + 1;                    // tiles this partition

    const ushort* Kg  = Kh + (size_t)bh * S_ * DK_;
    const ushort* Vg  = Vt + (size_t)bh * DK_ * S_;
    const float*  swp = SW + ((size_t)h * S_ + qrow) * S_;

    // fragment-major staging sources: block bb=(g*4+c), lane l holds
    // K[g*32+(l&31)][c*16+(l>>5)*8 +0..7]  (V^T analogous along keys)
    const ushort* kgp[2];
    const ushort* vgp[2];
#pragma unroll
    for (int j = 0; j < 2; ++j) {
        const int bb = w * 2 + j;
        const int g = bb >> 2, c = bb & 3;
        kgp[j] = Kg + (size_t)(g * 32 + ql) * DK_ + c * 16 + hi * 8;
        vgp[j] = Vg + (size_t)(g * 32 + ql) * S_  + c * 16 + hi * 8;
    }

#define ASTAGE(buf, k0)                                                          \
    do {                                                                         \
        _Pragma("unroll")                                                        \
        for (int j = 0; j < 2; ++j) {                                            \
            const int bb = w * 2 + j;                                            \
            __builtin_amdgcn_global_load_lds(                                    \
                (__attribute__((address_space(1))) const void*)(kgp[j] + (size_t)(k0) * DK_), \
                (__attribute__((address_space(3))) void*)&Ks[buf][bb * 512],     \
                16, 0, 0);                                                       \
            __builtin_amdgcn_global_load_lds(                                    \
                (__attribute__((address_space(1))) const void*)(vgp[j] + (k0)),  \
                (__attribute__((address_space(3))) void*)&Vs[buf][bb * 512],     \
                16, 0, 0);                                                       \
        }                                                                        \
    } while (0)

    // Q B-fragments: lane holds Q[q=qrow][dk = c*16 + hi*8 + i]
    short8 qf[4];
    {
        const ushort* Qg = Qh + ((size_t)bh * S_ + qrow) * DK_;
#pragma unroll
        for (int c = 0; c < 4; ++c) {
            union { int4 i; short8 s; } u;
            u.i = *reinterpret_cast<const int4*>(&Qg[c * 16 + hi * 8]);
            qf[c] = u.s;
        }
    }

    f32x16 accA, accB;
#pragma unroll
    for (int r = 0; r < 16; ++r) { accA[r] = 0.f; accB[r] = 0.f; }
    float mrow = -1e30f, lrow = 0.f;

    ASTAGE(0, t0 * 64);

#pragma unroll 1
    for (int kt = 0; kt < nt; ++kt) {
        const int cur = kt & 1;
        const int k0  = (t0 + kt) * 64;
        if (kt + 1 < nt) {
            ASTAGE(cur ^ 1, (t0 + kt + 1) * 64);
            asm volatile("s_waitcnt vmcnt(4)" ::: "memory");
        } else {
            asm volatile("s_waitcnt vmcnt(0)" ::: "memory");
        }
        __builtin_amdgcn_s_barrier();
        __builtin_amdgcn_sched_barrier(0);

        // ---- QK^T (swapped): lane-linear frag reads, zero conflicts ----
        f32x16 sc[2];
#pragma unroll
        for (int g = 0; g < 2; ++g) {
#pragma unroll
            for (int r = 0; r < 16; ++r) sc[g][r] = 0.f;
#pragma unroll
            for (int c = 0; c < 4; ++c) {
                const short8 kf = *reinterpret_cast<const short8*>(
                    &Ks[cur][((g * 4 + c) * 64 + lane) * 8]);
                sc[g] = __builtin_amdgcn_mfma_f32_32x32x16_bf16(kf, qf[c], sc[g], 0, 0, 0);
            }
        }

        // ---- state_weight gathers (lane's own q-row) ----
        float swv[2][16];
#pragma unroll
        for (int g = 0; g < 2; ++g)
#pragma unroll
            for (int j = 0; j < 4; ++j) {
                const float4 v = *reinterpret_cast<const float4*>(
                    &swp[k0 + g * 32 + hi * 4 + j * 8]);
                swv[g][j * 4 + 0] = v.x; swv[g][j * 4 + 1] = v.y;
                swv[g][j * 4 + 2] = v.z; swv[g][j * 4 + 3] = v.w;
            }

        // ---- masked scores + online softmax ----
        float pr[2][16];
        float tmax = -1e30f;
#pragma unroll
        for (int g = 0; g < 2; ++g)
#pragma unroll
            for (int r = 0; r < 16; ++r) {
                const int key = k0 + g * 32 + (r & 3) + ((r >> 2) << 3) + (hi << 2);
                const float s = (key < qrow) ? sc[g][r] * 0.125f + swv[g][r] : -1e30f;
                pr[g][r] = s;
                tmax = fmaxf(tmax, s);
            }
        tmax = fmaxf(tmax, __shfl_xor(tmax, 32, 64));
        const float mnew = fmaxf(mrow, tmax);
        const float corr = __expf(mrow - mnew);
        float psum = 0.f;
#pragma unroll
        for (int g = 0; g < 2; ++g)
#pragma unroll
            for (int r = 0; r < 16; ++r) {
                const float e = (pr[g][r] > -1e29f) ? __expf(pr[g][r] - mnew) : 0.f;
                pr[g][r] = e;
                psum += e;
            }
        psum += __shfl_xor(psum, 32, 64);
        lrow = lrow * corr + psum;
        mrow = mnew;
#pragma unroll
        for (int r = 0; r < 16; ++r) { accA[r] *= corr; accB[r] *= corr; }

        // ---- P -> bf16 B-fragments (pair pack + cross-half exchange) ----
        short8 paf[4];
#pragma unroll
        for (int g = 0; g < 2; ++g) {
            unsigned pk[8];
#pragma unroll
            for (int j = 0; j < 8; ++j)
                pk[j] = bf16rne(pr[g][2 * j]) | (bf16rne(pr[g][2 * j + 1]) << 16);
            unsigned x0 = (unsigned)__shfl_xor((int)pk[0], 32, 64);
            unsigned x1 = (unsigned)__shfl_xor((int)pk[1], 32, 64);
            unsigned x2 = (unsigned)__shfl_xor((int)pk[2], 32, 64);
            unsigned x3 = (unsigned)__shfl_xor((int)pk[3], 32, 64);
            unsigned x4 = (unsigned)__shfl_xor((int)pk[4], 32, 64);
            unsigned x5 = (unsigned)__shfl_xor((int)pk[5], 32, 64);
            unsigned x6 = (unsigned)__shfl_xor((int)pk[6], 32, 64);
            unsigned x7 = (unsigned)__shfl_xor((int)pk[7], 32, 64);
            union { unsigned u[4]; short8 s; } a0, a1;
            a0.u[0] = hi ? x2 : pk[0];
            a0.u[1] = hi ? x3 : pk[1];
            a0.u[2] = hi ? pk[2] : x0;
            a0.u[3] = hi ? pk[3] : x1;
            a1.u[0] = hi ? x6 : pk[4];
            a1.u[1] = hi ? x7 : pk[5];
            a1.u[2] = hi ? pk[6] : x4;
            a1.u[3] = hi ? pk[7] : x5;
            paf[g * 2 + 0] = a0.s;
            paf[g * 2 + 1] = a1.s;
        }

        // ---- PV (swapped): acc[dk][q] += V^T · P^T, lane-linear frags ----
#pragma unroll
        for (int cc = 0; cc < 4; ++cc) {
            const short8 va = *reinterpret_cast<const short8*>(
                &Vs[cur][((0 * 4 + cc) * 64 + lane) * 8]);
            const short8 vb = *reinterpret_cast<const short8*>(
                &Vs[cur][((1 * 4 + cc) * 64 + lane) * 8]);
            accA = __builtin_amdgcn_mfma_f32_32x32x16_bf16(va, paf[cc], accA, 0, 0, 0);
            accB = __builtin_amdgcn_mfma_f32_32x32x16_bf16(vb, paf[cc], accB, 0, 0, 0);
        }

        __builtin_amdgcn_sched_barrier(0);
        __builtin_amdgcn_s_barrier();
        __builtin_amdgcn_sched_barrier(0);
    }
#undef ASTAGE

    // ---- epilogue: normalized partial + (m,l) ----
    const float inv = (lrow > 0.f) ? 1.f / lrow : 0.f;
    ushort* crow_ = ctxP + (size_t)p * 4194304 +
                    ((size_t)b * S_ + qrow) * D_ + h * DK_;
#pragma unroll
    for (int g = 0; g < 4; ++g) {
        ushort4 oA, oB;
        oA.x = (ushort)bf16rne(accA[4 * g + 0] * inv);
        oA.y = (ushort)bf16rne(accA[4 * g + 1] * inv);
        oA.z = (ushort)bf16rne(accA[4 * g + 2] * inv);
        oA.w = (ushort)bf16rne(accA[4 * g + 3] * inv);
        oB.x = (ushort)bf16rne(accB[4 * g + 0] * inv);
        oB.y = (ushort)bf16rne(accB[4 * g + 1] * inv);
        oB.z = (ushort)bf16rne(accB[4 * g + 2] * inv);
        oB.w = (ushort)bf16rne(accB[4 * g + 3] * inv);
        *reinterpret_cast<ushort4*>(&crow_[g * 8 + hi * 4])      = oA;
        *reinterpret_cast<ushort4*>(&crow_[g * 8 + hi * 4 + 32]) = oB;
    }
    if (hi == 0) {
        float2 v; v.x = mrow; v.y = lrow;
        ml[((size_t)p * 64 + bh) * 1024 + qrow] = v;
    }
}

// ---------------------------------------------------------------------------
// Merge the two split-K partials: out = w0*o0 + w1*o1, w_p ∝ l_p e^{m_p-m}.
// ---------------------------------------------------------------------------
__global__ __launch_bounds__(256) void attn_merge(
    const ushort* __restrict__ ctxP, const float2* __restrict__ ml,
    ushort* __restrict__ ctx)
{
    const size_t idx = ((size_t)blockIdx.x * 256 + threadIdx.x) * 8;
    const int col = (int)(idx & 1023);
    const int row = (int)(idx >> 10);          // b*S + s
    const int b = row >> 10, s = row & 1023;
    const int h = col >> 6;
    const int bh = b * 16 + h;
    const float2 ml0 = ml[(size_t)bh * 1024 + s];
    const float2 ml1 = ml[(size_t)(64 + bh) * 1024 + s];
    const float m  = fmaxf(ml0.x, ml1.x);
    const float a0 = ml0.y * __expf(ml0.x - m);
    const float a1 = ml1.y * __expf(ml1.x - m);
    const float d  = a0 + a1;
    const float w0 = (d > 0.f) ? a0 / d : 0.f;
    const float w1 = (d > 0.f) ? a1 / d : 0.f;
    union { int4 v; ushort u[8]; } p0, p1, o;
    p0.v = *reinterpret_cast<const int4*>(ctxP + idx);
    p1.v = *reinterpret_cast<const int4*>(ctxP + 4194304 + idx);
#pragma unroll
    for (int i = 0; i < 8; ++i) {
        const float f0 = __uint_as_float((unsigned)p0.u[i] << 16);
        const float f1 = __uint_as_float((unsigned)p1.u[i] << 16);
        o.u[i] = (ushort)bf16rne(w0 * f0 + w1 * f1);
    }
    *reinterpret_cast<int4*>(ctx + idx) = o.v;
}

// ---------------------------------------------------------------------------
// LayerNorm over last dim (1024).
// ---------------------------------------------------------------------------
__global__ __launch_bounds__(256) void layernorm_k(
    const float* __restrict__ x, const float* __restrict__ gamma,
    const float* __restrict__ beta, float* __restrict__ out)
{
    const int row = blockIdx.x;
    const int t   = threadIdx.x;
    const float4 v = *reinterpret_cast<const float4*>(&x[(size_t)row * D_ + (t << 2)]);
    float sum = v.x + v.y + v.z + v.w;
    float sq  = v.x * v.x + v.y * v.y + v.z * v.z + v.w * v.w;
#pragma unroll
    for (int w = 1; w < 64; w <<= 1) {
        sum += __shfl_xor(sum, w, 64);
        sq  += __shfl_xor(sq,  w, 64);
    }
    __shared__ float red[8];
    const int wid = t >> 6;
    if ((t & 63) == 0) { red[wid] = sum; red[wid + 4] = sq; }
    __syncthreads();
    sum = red[0] + red[1] + red[2] + red[3];
    sq  = red[4] + red[5] + red[6] + red[7];
    const float mu  = sum * (1.f / 1024.f);
    const float var = sq * (1.f / 1024.f) - mu * mu;
    const float rs  = rsqrtf(var + 1e-5f);
    const float4 gm = *reinterpret_cast<const float4*>(&gamma[t << 2]);
    const float4 bt = *reinterpret_cast<const float4*>(&beta[t << 2]);
    float4 o;
    o.x = (v.x - mu) * rs * gm.x + bt.x;
    o.y = (v.y - mu) * rs * gm.y + bt.y;
    o.z = (v.z - mu) * rs * gm.z + bt.z;
    o.w = (v.w - mu) * rs * gm.w + bt.w;
    *reinterpret_cast<float4*>(&out[(size_t)row * D_ + (t << 2)]) = o;
}

// ---------------------------------------------------------------------------
extern "C" void kernel_launch(void* const* d_in, const int* in_sizes, int n_in,
                              void* d_out, int out_size, void* d_ws, size_t ws_size,
                              hipStream_t stream)
{
    const float* query  = (const float*)d_in[0];
    const float* key    = (const float*)d_in[1];
    const float* values = (const float*)d_in[2];
    const float* SW     = (const float*)d_in[4];
    const float* Wq     = (const float*)d_in[5];
    const float* bq     = (const float*)d_in[6];
    const float* Wv     = (const float*)d_in[7];
    const float* bv     = (const float*)d_in[8];
    const float* Wo     = (const float*)d_in[9];
    const float* bo     = (const float*)d_in[10];
    const float* gamma  = (const float*)d_in[11];
    const float* beta   = (const float*)d_in[12];

    char* ws = (char*)d_ws;
    const size_t MB = 1024 * 1024;
    ushort* qbf  = (ushort*)(ws);              //  8 MB bf16 [4096][1024] (qbf|kbf contiguous)
    ushort* kbf  = (ushort*)(ws +  8 * MB);
    ushort* vbf  = (ushort*)(ws + 16 * MB);
    ushort* Wqt  = (ushort*)(ws + 24 * MB);
    ushort* Wvt  = (ushort*)(ws + 26 * MB);
    ushort* Wot  = (ushort*)(ws + 28 * MB);
    ushort* Qh   = (ushort*)(ws + 30 * MB);    //  8 MB bf16 [bh][S][DK]
    ushort* Kh   = (ushort*)(ws + 38 * MB);
    ushort* Vt   = (ushort*)(ws + 46 * MB);    //  8 MB bf16 [bh][DK][S]
    float2* ml   = (float2*)(ws + 54 * MB);    //  1 MB (m,l)[2][64][1024]
    ushort* ctxP = qbf;                        // partials overlay qbf|kbf (16 MB)
    ushort* ctxm = vbf;                        // merged ctx overlays vbf (8 MB)
    float*  xbf  = (float*)(ws + 30 * MB);     // 16 MB fp32, overlays Qh|Kh post-attn

    const dim3 blk(256);

    cvt3_bf16<<<dim3(6144), blk, 0, stream>>>(query, key, values, qbf);
    transpose_cvt3<<<dim3(32, 32, 3), blk, 0, stream>>>(Wq, Wv, Wo, Wqt, Wvt, Wot);

    // merged Q|K projection (shared Wq/bq), M = 8192
    gemm_mfma<1><<<dim3(1024), blk, 0, stream>>>(qbf, Wqt, bq, nullptr, Qh, Kh);
    gemm_mfma<2><<<dim3(512),  blk, 0, stream>>>(vbf, Wvt, bv, nullptr, Vt, nullptr);

    attn_mfma<<<dim3(1024), blk, 0, stream>>>(Qh, Kh, Vt, SW, ctxP, ml);
    attn_merge<<<dim3(2048), blk, 0, stream>>>(ctxP, ml, ctxm);

    gemm_mfma<0><<<dim3(512), blk, 0, stream>>>(ctxm, Wot, bo, query, xbf, nullptr);

    layernorm_k<<<dim3(4096), blk, 0, stream>>>(xbf, gamma, beta, (float*)d_out);
}